// Round 7
// baseline (123.034 us; speedup 1.0000x reference)
//
#include <hip/hip_runtime.h>

typedef __attribute__((ext_vector_type(8))) short bf16x8;
typedef __attribute__((ext_vector_type(4))) float f32x4;

#define AS3 __attribute__((address_space(3)))
#define AS1 __attribute__((address_space(1)))

__device__ __forceinline__ unsigned short f2bf(float f) {
  unsigned u = __float_as_uint(f);
  u += 0x7fffu + ((u >> 16) & 1u);
  return (unsigned short)(u >> 16);
}
__device__ __forceinline__ float bf2f(unsigned short v) {
  return __uint_as_float((unsigned)v << 16);
}

// ---------------- kernel 1: transpose + pad + bf16 + border-zero + pool partials
// x[b][c][y][x] -> xTp[b][(y+1)*66+(x+1)][c] bf16; border pads zeroed here;
// per-(b,y) channel partial sums -> part[(b*64+y)*256+c]
__global__ void transpose_kernel(const float* __restrict__ x,
                                 unsigned short* __restrict__ xTp,
                                 float* __restrict__ part) {
  __shared__ unsigned short tb[64][258];
  __shared__ float redf[4][256];
  const int blk = blockIdx.x;
  const int b = blk >> 6, y = blk & 63;
  const int t = threadIdx.x;
  const int l = t & 63, w = t >> 6;
  const int coff = l >> 4;          // 0..3 channel sub-offset
  const int x4 = (l & 15) << 2;     // 0..60 x base
  const float* src = x + (size_t)b * 256 * 4096 + (size_t)y * 64;
#pragma unroll 4
  for (int i = 0; i < 16; ++i) {
    const int c = w * 64 + i * 4 + coff;
    const float4 v = *reinterpret_cast<const float4*>(&src[(size_t)c * 4096 + x4]);
    tb[x4 + 0][c] = f2bf(v.x);
    tb[x4 + 1][c] = f2bf(v.y);
    tb[x4 + 2][c] = f2bf(v.z);
    tb[x4 + 3][c] = f2bf(v.w);
  }
  __syncthreads();
  unsigned short* dstb = xTp + (size_t)b * (4356 * 256);
  unsigned short* dst = dstb + ((size_t)(y + 1) * 66 + 1) * 256;
  float s0 = 0.f, s1 = 0.f, s2 = 0.f, s3 = 0.f;
#pragma unroll 4
  for (int i = 0; i < 16; ++i) {
    const int xx = w * 16 + i;
    ushort2 v0 = *(const ushort2*)&tb[xx][l * 4];
    ushort2 v1 = *(const ushort2*)&tb[xx][l * 4 + 2];
    s0 += bf2f(v0.x); s1 += bf2f(v0.y); s2 += bf2f(v1.x); s3 += bf2f(v1.y);
    ushort4 v = {v0.x, v0.y, v1.x, v1.y};
    *(ushort4*)&dst[(size_t)xx * 256 + l * 4] = v;
  }
  redf[w][l * 4 + 0] = s0;
  redf[w][l * 4 + 1] = s1;
  redf[w][l * 4 + 2] = s2;
  redf[w][l * 4 + 3] = s3;
  // border pads: row (y+1) cols 0 and 65; blocks y==0/63 do rows 0/65
  unsigned short* rowpad = dstb + ((size_t)(y + 1) * 66) * 256;
  rowpad[t] = 0;
  rowpad[65 * 256 + t] = 0;
  if (y == 0)
    for (int xx = 0; xx < 66; ++xx) dstb[(size_t)xx * 256 + t] = 0;
  if (y == 63)
    for (int xx = 0; xx < 66; ++xx) dstb[(size_t)(65 * 66 + xx) * 256 + t] = 0;
  __syncthreads();
  part[((size_t)(b * 64 + y)) * 256 + t] =
      redf[0][t] + redf[1][t] + redf[2][t] + redf[3][t];
}

// ---------------- kernel 1c: finish pool ----------
__global__ void poolfin_kernel(const float* __restrict__ part,
                               float* __restrict__ pooled) {
  const int b = blockIdx.x, c = threadIdx.x;
  float s = 0.f;
  for (int y = 0; y < 64; ++y) s += part[((size_t)(b * 64 + y)) * 256 + c];
  pooled[b * 256 + c] = s * (1.0f / 4096.0f);
}

// ---------------- kernel 2: attention MLP + softmax ----------------
__global__ void attn_kernel(const float* __restrict__ pooled,
                            const float* __restrict__ w1,
                            const float* __restrict__ bng,
                            const float* __restrict__ bnb,
                            const float* __restrict__ bnm,
                            const float* __restrict__ bnv,
                            const float* __restrict__ w2,
                            float* __restrict__ att) {
  __shared__ float hbuf[256];
  const int t = threadIdx.x;
  const int b = t >> 4, i = t & 15;
  float s = 0.f;
  for (int c = 0; c < 256; ++c) s += pooled[b * 256 + c] * w1[i * 256 + c];
  float h = (s - bnm[i]) * rsqrtf(bnv[i] + 1e-5f) * bng[i] + bnb[i];
  hbuf[t] = fmaxf(h, 0.f);
  __syncthreads();
  if (t < 64) {
    const int bb = t >> 2, k = t & 3;
    float l = 0.f;
    for (int j = 0; j < 16; ++j) l += hbuf[bb * 16 + j] * w2[k * 16 + j];
    float m = l;
    m = fmaxf(m, __shfl_xor(m, 1, 64));
    m = fmaxf(m, __shfl_xor(m, 2, 64));
    float e = expf(l - m);
    float sum = e;
    sum += __shfl_xor(sum, 1, 64);
    sum += __shfl_xor(sum, 2, 64);
    att[bb * 4 + k] = e / sum;
  }
}

// ---------------- kernel 3: aggregate per-sample kernels ----------------
__global__ void agg_kernel(const float* __restrict__ att,
                           const float* __restrict__ wgt,
                           unsigned short* __restrict__ agg) {
  const int o = blockIdx.x;    // 256
  const int bh = blockIdx.y;   // 0..1
  const int c = threadIdx.x;   // 256
  float w[4][9];
#pragma unroll
  for (int k = 0; k < 4; ++k) {
    const float* wp = wgt + ((size_t)((k << 8) + o) * 256 + c) * 9;
#pragma unroll
    for (int t = 0; t < 9; ++t) w[k][t] = wp[t];
  }
  __shared__ float attS[64];
  if (c < 64) attS[c] = att[c];
  __syncthreads();
#pragma unroll 1
  for (int b = bh * 8; b < bh * 8 + 8; ++b) {
    const float a0 = attS[b * 4 + 0], a1 = attS[b * 4 + 1];
    const float a2 = attS[b * 4 + 2], a3 = attS[b * 4 + 3];
#pragma unroll
    for (int t = 0; t < 9; ++t) {
      const float v = a0 * w[0][t] + a1 * w[1][t] + a2 * w[2][t] + a3 * w[3][t];
      agg[(((size_t)(b * 9 + t) * 256) + o) * 256 + c] = f2bf(v);
    }
  }
}

// ---------------- kernel 4: per-sample implicit-GEMM conv (bf16 MFMA) ----
// tile 256(p) x 128(cout); 4 waves (2Mx2N) of 128x64 (8x4 frags).
// Software-pipelined fragments: ds_read(tap t+1) overlaps MFMA(tap t).
// A-halo staged once per c0 (reused 9 taps); B ring-4 depth-3, vmcnt(2).
__global__ __launch_bounds__(256, 2) void conv_kernel(
    const unsigned short* __restrict__ xTp,
    const unsigned short* __restrict__ agg,
    float* __restrict__ out) {
  // A: 448 rows x 64B = 28672 B ; B: 4 slots x 8192 B
  __shared__ unsigned short lds[448 * 32 + 4 * 128 * 32];
  AS3 char* ldsA3 = (AS3 char*)lds;
  AS3 char* ldsB3 = ((AS3 char*)lds) + 28672;

  const int bid = blockIdx.x;
  const int b = bid & 15;   // XCD = b%8
  const int rest = bid >> 4;
  const int mt = rest >> 1;  // 0..15
  const int nh = rest & 1;
  const int p0 = mt << 8;
  const int rowA0 = mt * 264;

  const int tid = threadIdx.x;   // 0..255
  const int lane = tid & 63;
  const int wave = tid >> 6;     // 0..3
  const int wm = wave >> 1;      // 0..1 (M half, 128 rows)
  const int wn = wave & 1;       // 0..1 (N half, 64 cols)

  const int srow = tid >> 2;     // 0..63
  const int scol = ((tid & 3) ^ ((tid >> 3) & 3)) << 3;
  const int sdst = srow * 64 + (tid & 3) * 16;

  const unsigned short* xbs =
      xTp + (size_t)b * (4356 * 256) + (size_t)rowA0 * 256 + scol;
  const unsigned short* aggs =
      agg + ((size_t)(b * 9) * 256 + nh * 128 + srow) * 256 + scol;

  auto stageA = [&](int c0) {
#pragma unroll
    for (int i = 0; i < 7; ++i) {
      const int h = srow + (i << 6);
      const int hs = h > 395 ? 395 : h;
      __builtin_amdgcn_global_load_lds(
          (const AS1 void*)(xbs + (size_t)hs * 256 + c0 * 32),
          (AS3 void*)(ldsA3 + sdst + (i << 12)), 16, 0, 0);
    }
  };
  auto stageB = [&](int c02, int tap2, int slot) {
#pragma unroll
    for (int j = 0; j < 2; ++j) {
      __builtin_amdgcn_global_load_lds(
          (const AS1 void*)(aggs + tap2 * 65536 + (j << 14) + c02 * 32),
          (AS3 void*)(ldsB3 + slot * 8192 + sdst + (j << 12)), 16, 0, 0);
    }
  };

  const int l15 = lane & 15;
  const int lhi = lane >> 4;
  const int hb0 = wm * 132 + l15;
  const int rslotB = (lhi ^ ((l15 >> 1) & 3)) << 4;
  int boffs[4];
#pragma unroll
  for (int n = 0; n < 4; ++n)
    boffs[n] = 28672 + (wn * 64 + n * 16 + l15) * 64 + rslotB;

  f32x4 acc[8][4];
#pragma unroll
  for (int m = 0; m < 8; ++m)
#pragma unroll
    for (int n = 0; n < 4; ++n) acc[m][n] = (f32x4){0.f, 0.f, 0.f, 0.f};

#define LDFRAG(AF, BF, tap)                                                   \
  {                                                                           \
    const int dy_ = (tap) / 3, dx_ = (tap) % 3;                               \
    const int slotR_ = (c0 + (tap)) & 3;                                      \
    _Pragma("unroll") for (int m = 0; m < 8; ++m) {                           \
      const int h_ = hb0 + ((m >> 2) + dy_) * 66 + (m & 3) * 16 + dx_;        \
      AF[m] = *(const bf16x8*)((const char*)lds + h_ * 64 +                   \
                               ((lhi ^ ((h_ >> 1) & 3)) << 4));               \
    }                                                                         \
    _Pragma("unroll") for (int n = 0; n < 4; ++n) {                           \
      BF[n] = *(const bf16x8*)((const char*)lds + slotR_ * 8192 + boffs[n]);  \
    }                                                                         \
  }

#define STAGEBT(t)                                                \
  {                                                               \
    int c02_, tap2_;                                              \
    if ((t) <= 5) { c02_ = c0; tap2_ = (t) + 3; }                 \
    else { c02_ = c0 + 1; tap2_ = (t) - 6; }                      \
    if (c02_ > 7) { c02_ = 7; tap2_ = 8; }                        \
    stageB(c02_, tap2_, (c0 + (t) + 3) & 3);                      \
  }

#define MFMACL(AF, BF)                                                        \
  _Pragma("unroll") for (int m = 0; m < 8; ++m)                               \
  _Pragma("unroll") for (int n = 0; n < 4; ++n)                               \
      acc[m][n] =                                                             \
          __builtin_amdgcn_mfma_f32_16x16x32_bf16(AF[m], BF[n], acc[m][n], 0, 0, 0);

#define TAPITER(t, AFc, BFc, AFn, BFn, PREF)                         \
  {                                                                  \
    if ((t) > 0) {                                                   \
      asm volatile("s_waitcnt vmcnt(2)" ::: "memory");               \
      __builtin_amdgcn_s_barrier();                                  \
      __builtin_amdgcn_sched_barrier(0);                             \
    }                                                                \
    STAGEBT(t);                                                      \
    if (PREF) LDFRAG(AFn, BFn, (t) + 1);                             \
    __builtin_amdgcn_s_setprio(1);                                   \
    MFMACL(AFc, BFc);                                                \
    __builtin_amdgcn_s_setprio(0);                                   \
  }

  stageB(0, 0, 0);
  stageB(0, 1, 1);
  stageB(0, 2, 2);

#pragma unroll 1
  for (int c0 = 0; c0 < 8; ++c0) {
    bf16x8 afr0[8], afr1[8], bfr0[4], bfr1[4];
    __builtin_amdgcn_s_barrier();  // all waves done reading A[c0-1]
    stageA(c0);
    asm volatile("s_waitcnt vmcnt(0)" ::: "memory");
    __builtin_amdgcn_s_barrier();
    __builtin_amdgcn_sched_barrier(0);
    LDFRAG(afr0, bfr0, 0);
    TAPITER(0, afr0, bfr0, afr1, bfr1, 1);
    TAPITER(1, afr1, bfr1, afr0, bfr0, 1);
    TAPITER(2, afr0, bfr0, afr1, bfr1, 1);
    TAPITER(3, afr1, bfr1, afr0, bfr0, 1);
    TAPITER(4, afr0, bfr0, afr1, bfr1, 1);
    TAPITER(5, afr1, bfr1, afr0, bfr0, 1);
    TAPITER(6, afr0, bfr0, afr1, bfr1, 1);
    TAPITER(7, afr1, bfr1, afr0, bfr0, 1);
    TAPITER(8, afr0, bfr0, afr1, bfr1, 0);
  }

  // epilogue: D row=(lane>>4)*4+reg is p, col=lane&15 is cout
#pragma unroll
  for (int m = 0; m < 8; ++m) {
    const int p = p0 + wm * 128 + (m >> 2) * 64 + (m & 3) * 16 + (lhi << 2);
#pragma unroll
    for (int n = 0; n < 4; ++n) {
      const int co = nh * 128 + wn * 64 + n * 16 + l15;
      float* dst = out + ((size_t)(b * 256 + co) << 12) + p;
      *reinterpret_cast<f32x4*>(dst) = acc[m][n];
    }
  }
}

extern "C" void kernel_launch(void* const* d_in, const int* in_sizes, int n_in,
                              void* d_out, int out_size, void* d_ws, size_t ws_size,
                              hipStream_t stream) {
  const float* x = (const float*)d_in[0];
  const float* w1 = (const float*)d_in[1];
  const float* bng = (const float*)d_in[2];
  const float* bnb = (const float*)d_in[3];
  const float* bnm = (const float*)d_in[4];
  const float* bnv = (const float*)d_in[5];
  const float* w2 = (const float*)d_in[6];
  const float* wgt = (const float*)d_in[7];
  float* out = (float*)d_out;

  char* ws = (char*)d_ws;
  const size_t xtp_bytes = (size_t)16 * 4356 * 256 * 2;    // 35,684,352
  const size_t agg_bytes = (size_t)16 * 9 * 256 * 256 * 2; // 18,874,368
  unsigned short* xTp = (unsigned short*)ws;
  unsigned short* agg = (unsigned short*)(ws + xtp_bytes);
  float* pooled = (float*)(ws + xtp_bytes + agg_bytes);
  float* att = (float*)(ws + xtp_bytes + agg_bytes + 16384);
  float* part = (float*)(ws + xtp_bytes + agg_bytes + 20480);

  transpose_kernel<<<1024, 256, 0, stream>>>(x, xTp, part);
  poolfin_kernel<<<16, 256, 0, stream>>>(part, pooled);
  attn_kernel<<<1, 256, 0, stream>>>(pooled, w1, bng, bnb, bnm, bnv, w2, att);
  agg_kernel<<<dim3(256, 2), 256, 0, stream>>>(att, wgt, agg);
  conv_kernel<<<512, 256, 0, stream>>>(xTp, agg, out);
}